// Round 17
// baseline (533.308 us; speedup 1.0000x reference)
//
#include <hip/hip_runtime.h>
#include <hip/hip_bf16.h>

#define NVOX 200000
#define DIM 96
#define KVOL 343
#define NEDGE 3200000
#define HID 384
#define TM 32
#define NBKT (NVOX / TM)        // 6250 block-buckets
#define SBCAP 128               // per-(bucket,xcd) capacity
#define ROWCAP 48               // per-voxel capacity; mean 16
#define XCC_IMM 63508           // hwreg(HW_REG_XCC_ID=20, offset 0, size 32)
#define W8DW (KVOL * DIM / 4)   // 8232 dwords of fp8 w_dw

typedef __attribute__((ext_vector_type(8))) __bf16 bf16x8;
typedef __attribute__((ext_vector_type(4))) __bf16 bf16x4;
typedef __attribute__((ext_vector_type(4))) float f32x4;
typedef __attribute__((ext_vector_type(2))) float f32x2;
typedef __attribute__((ext_vector_type(4))) int i32x4;
typedef __attribute__((ext_vector_type(4))) unsigned u32x4;
typedef __attribute__((ext_vector_type(2))) unsigned u32x2;

// ---------------- prep: feats->bf16 + fp8, w_dw->fp8, w1/w2->bf16 transposed ----------------
__global__ void prep(const float* __restrict__ feats, const float* __restrict__ w1,
                     const float* __restrict__ w2, const float* __restrict__ w_dw,
                     __bf16* __restrict__ featsb, unsigned* __restrict__ featsf8,
                     __hip_bfloat16* __restrict__ w1t, __hip_bfloat16* __restrict__ w2t,
                     unsigned* __restrict__ wdw8, int* __restrict__ bcnt) {
    int t = blockIdx.x * 256 + threadIdx.x;   // NVOX*DIM/4 = 4.8M exact
    f32x4 v = __builtin_nontemporal_load((const f32x4*)(feats + t * 4));
    bf16x4 o;
    o[0] = (__bf16)v.x; o[1] = (__bf16)v.y; o[2] = (__bf16)v.z; o[3] = (__bf16)v.w;
    __builtin_nontemporal_store(o, (bf16x4*)(featsb + t * 4));
    int pk = __builtin_amdgcn_cvt_pk_fp8_f32(v.x, v.y, 0, false);
    pk = __builtin_amdgcn_cvt_pk_fp8_f32(v.z, v.w, pk, true);
    __builtin_nontemporal_store((unsigned)pk, &featsf8[t]);
    if (t < HID * DIM) {
        int n1 = t / DIM, k1 = t % DIM;
        w1t[t] = __float2bfloat16(w1[k1 * HID + n1]);
        int n2 = t / HID, k2 = t % HID;
        w2t[t] = __float2bfloat16(w2[k2 * DIM + n2]);
    }
    if (t < W8DW) {
        f32x4 w = *(const f32x4*)(w_dw + t * 4);
        int wp = __builtin_amdgcn_cvt_pk_fp8_f32(w.x, w.y, 0, false);
        wp = __builtin_amdgcn_cvt_pk_fp8_f32(w.z, w.w, wp, true);
        wdw8[t] = (unsigned)wp;
    }
    if (t < NBKT * 8) bcnt[t] = 0;
}

// ---------------- scatter into XCD-private block-buckets ----------------
__global__ void scatter_B(const i32x4* __restrict__ in4, const i32x4* __restrict__ out4,
                          const i32x4* __restrict__ k4, int* __restrict__ bcnt,
                          unsigned* __restrict__ sb) {
    int t = blockIdx.x * 256 + threadIdx.x;   // NEDGE/4 exact
    unsigned xcd = (unsigned)__builtin_amdgcn_s_getreg(XCC_IMM) & 7u;
    i32x4 i = __builtin_nontemporal_load(&in4[t]);
    i32x4 o = __builtin_nontemporal_load(&out4[t]);
    i32x4 k = __builtin_nontemporal_load(&k4[t]);
    int b, d;
    b = ((unsigned)o.x >> 5) * 8 + xcd;
    d = atomicAdd(&bcnt[b], 1);
    if (d < SBCAP) sb[b * SBCAP + d] = (unsigned)i.x | ((unsigned)k.x << 18) | ((unsigned)(o.x & 31) << 27);
    b = ((unsigned)o.y >> 5) * 8 + xcd;
    d = atomicAdd(&bcnt[b], 1);
    if (d < SBCAP) sb[b * SBCAP + d] = (unsigned)i.y | ((unsigned)k.y << 18) | ((unsigned)(o.y & 31) << 27);
    b = ((unsigned)o.z >> 5) * 8 + xcd;
    d = atomicAdd(&bcnt[b], 1);
    if (d < SBCAP) sb[b * SBCAP + d] = (unsigned)i.z | ((unsigned)k.z << 18) | ((unsigned)(o.z & 31) << 27);
    b = ((unsigned)o.w >> 5) * 8 + xcd;
    d = atomicAdd(&bcnt[b], 1);
    if (d < SBCAP) sb[b * SBCAP + d] = (unsigned)i.w | ((unsigned)k.w << 18) | ((unsigned)(o.w & 31) << 27);
}

// ---------------- fused sort + fp8-gather (w in LDS) + LN + MLP ----------------
__global__ __launch_bounds__(256, 4) void fused_all(
    const unsigned char* __restrict__ featsf8, const __bf16* __restrict__ featsb,
    const unsigned* __restrict__ wdw8, const float* __restrict__ b_dw,
    const float* __restrict__ ln_w, const float* __restrict__ ln_b,
    const __hip_bfloat16* __restrict__ w1t, const float* __restrict__ b1,
    const __hip_bfloat16* __restrict__ w2t, const float* __restrict__ b2,
    const unsigned* __restrict__ sb, const int* __restrict__ bcnt,
    float* __restrict__ out)
{
    __shared__ __hip_bfloat16 At[TM][104];                 //  6,656 B
    __shared__ __align__(16) char shb[TM * 200 * 2];       // 12,800 B: rowlist+rowcnt | Ht half
    __shared__ __align__(16) unsigned w8[W8DW];            // 32,928 B: fp8 w_dw
    __hip_bfloat16 (*Ht)[200] = (__hip_bfloat16 (*)[200])shb;
    unsigned (*rowlist)[ROWCAP] = (unsigned (*)[ROWCAP])shb;   // 6,144 B
    int* rowcnt = (int*)(shb + 32 * ROWCAP * 4);               //   128 B

    const int t   = threadIdx.x;
    const int blk = blockIdx.x;

    if (t < 32) rowcnt[t] = 0;
    // ---- stage fp8 w_dw into LDS (coalesced, no TA cost later) ----
    for (int i = t; i < W8DW; i += 256) w8[i] = wdw8[i];
    __syncthreads();

    // ---- counting-sort the block's 8 sub-buckets into per-row LDS lists ----
    #pragma unroll
    for (int q = 0; q < 8; ++q) {
        int cq = bcnt[blk * 8 + q];
        if (cq > SBCAP) cq = SBCAP;
        const unsigned* reg = sb + (blk * 8 + q) * SBCAP;
        for (int i = t; i < cq; i += 256) {
            unsigned r = reg[i];
            int row = (int)(r >> 27);
            int d = atomicAdd(&rowcnt[row], 1);
            if (d < ROWCAP) rowlist[row][d] = r;
        }
    }
    __syncthreads();

    // ---- gather: 8 threads/voxel = 4 parts x 2 edge-halves ----
    // part p owns channels [p*16, p*16+16) U [64+p*8, 64+p*8+8)
    {
        const int row  = t >> 3;        // 0..31
        const int sub  = t & 7;
        const int part = sub & 3;
        const int half = sub >> 2;
        const int c16  = part * 16;
        const int c8b  = 64 + part * 8;

        int c = rowcnt[row];
        if (c > ROWCAP) c = ROWCAP;

        float xa[24];
        #pragma unroll
        for (int j = 0; j < 24; ++j) xa[j] = 0.f;

        const unsigned char* f8base = featsf8;
        const unsigned char* w8b = (const unsigned char*)w8;
        const unsigned* rl = rowlist[row];

        const int e_lo = half ? (c >> 1) : 0;
        const int e_hi = half ? c : (c >> 1);

#define LDE(FQ, FD, WQ, WD, ee) { unsigned rr = rl[ee]; \
        const unsigned char* f8r = f8base + (unsigned)(rr & 0x3FFFFu) * 96u; \
        const unsigned char* w8r = w8b + ((rr >> 18) & 0x1FFu) * 96u; \
        FQ = *(const u32x4*)(f8r + c16); \
        FD = *(const u32x2*)(f8r + c8b); \
        WQ = *(const u32x4*)(w8r + c16); \
        WD = *(const u32x2*)(w8r + c8b); }

#define ACC(FQ, FD, WQ, WD) { \
        float fa[24], wa[24]; \
        *(f32x2*)&fa[0]  = __builtin_amdgcn_cvt_pk_f32_fp8(FQ.x, false); \
        *(f32x2*)&fa[2]  = __builtin_amdgcn_cvt_pk_f32_fp8(FQ.x, true);  \
        *(f32x2*)&fa[4]  = __builtin_amdgcn_cvt_pk_f32_fp8(FQ.y, false); \
        *(f32x2*)&fa[6]  = __builtin_amdgcn_cvt_pk_f32_fp8(FQ.y, true);  \
        *(f32x2*)&fa[8]  = __builtin_amdgcn_cvt_pk_f32_fp8(FQ.z, false); \
        *(f32x2*)&fa[10] = __builtin_amdgcn_cvt_pk_f32_fp8(FQ.z, true);  \
        *(f32x2*)&fa[12] = __builtin_amdgcn_cvt_pk_f32_fp8(FQ.w, false); \
        *(f32x2*)&fa[14] = __builtin_amdgcn_cvt_pk_f32_fp8(FQ.w, true);  \
        *(f32x2*)&fa[16] = __builtin_amdgcn_cvt_pk_f32_fp8(FD.x, false); \
        *(f32x2*)&fa[18] = __builtin_amdgcn_cvt_pk_f32_fp8(FD.x, true);  \
        *(f32x2*)&fa[20] = __builtin_amdgcn_cvt_pk_f32_fp8(FD.y, false); \
        *(f32x2*)&fa[22] = __builtin_amdgcn_cvt_pk_f32_fp8(FD.y, true);  \
        *(f32x2*)&wa[0]  = __builtin_amdgcn_cvt_pk_f32_fp8(WQ.x, false); \
        *(f32x2*)&wa[2]  = __builtin_amdgcn_cvt_pk_f32_fp8(WQ.x, true);  \
        *(f32x2*)&wa[4]  = __builtin_amdgcn_cvt_pk_f32_fp8(WQ.y, false); \
        *(f32x2*)&wa[6]  = __builtin_amdgcn_cvt_pk_f32_fp8(WQ.y, true);  \
        *(f32x2*)&wa[8]  = __builtin_amdgcn_cvt_pk_f32_fp8(WQ.z, false); \
        *(f32x2*)&wa[10] = __builtin_amdgcn_cvt_pk_f32_fp8(WQ.z, true);  \
        *(f32x2*)&wa[12] = __builtin_amdgcn_cvt_pk_f32_fp8(WQ.w, false); \
        *(f32x2*)&wa[14] = __builtin_amdgcn_cvt_pk_f32_fp8(WQ.w, true);  \
        *(f32x2*)&wa[16] = __builtin_amdgcn_cvt_pk_f32_fp8(WD.x, false); \
        *(f32x2*)&wa[18] = __builtin_amdgcn_cvt_pk_f32_fp8(WD.x, true);  \
        *(f32x2*)&wa[20] = __builtin_amdgcn_cvt_pk_f32_fp8(WD.y, false); \
        *(f32x2*)&wa[22] = __builtin_amdgcn_cvt_pk_f32_fp8(WD.y, true);  \
        _Pragma("unroll") for (int j = 0; j < 24; ++j) xa[j] += fa[j] * wa[j]; }

        u32x4 Aq, Bq, Awq, Bwq; u32x2 Ad, Bd, Awd, Bwd;
        int e = e_lo;
        if (e + 2 <= e_hi) {
            LDE(Aq, Ad, Awq, Awd, e); LDE(Bq, Bd, Bwq, Bwd, e + 1);
            e += 2;
            for (; e + 2 <= e_hi; e += 2) {
                u32x4 Cq, Dq, Cwq, Dwq; u32x2 Cd, Dd, Cwd, Dwd;
                LDE(Cq, Cd, Cwq, Cwd, e); LDE(Dq, Dd, Dwq, Dwd, e + 1);
                ACC(Aq, Ad, Awq, Awd); ACC(Bq, Bd, Bwq, Bwd);
                Aq = Cq; Ad = Cd; Awq = Cwq; Awd = Cwd;
                Bq = Dq; Bd = Dd; Bwq = Dwq; Bwd = Dwd;
            }
            ACC(Aq, Ad, Awq, Awd); ACC(Bq, Bd, Bwq, Bwd);
        }
        if (e < e_hi) {
            LDE(Aq, Ad, Awq, Awd, e);
            ACC(Aq, Ad, Awq, Awd);
        }
#undef LDE
#undef ACC

        // combine edge-halves (lane bit 2)
        #pragma unroll
        for (int j = 0; j < 24; ++j) xa[j] += __shfl_xor(xa[j], 4);

        // + b_dw, LayerNorm stats across 4 parts (lane bits 0-1)
        float s = 0.f, s2 = 0.f;
        #pragma unroll
        for (int j = 0; j < 24; ++j) {
            int ch = (j < 16) ? (c16 + j) : (c8b + j - 16);
            float x = xa[j] + b_dw[ch];
            xa[j] = x;
            s += x; s2 += x * x;
        }
        s  += __shfl_xor(s, 1);  s  += __shfl_xor(s, 2);
        s2 += __shfl_xor(s2, 1); s2 += __shfl_xor(s2, 2);
        float mean = s * (1.f / 96.f);
        float var  = s2 * (1.f / 96.f) - mean * mean;
        float rstd = rsqrtf(var + 1e-6f);

        if (half == 0) {
            #pragma unroll
            for (int jj = 0; jj < 3; ++jj) {
                bf16x8 pack;
                #pragma unroll
                for (int j = 0; j < 8; ++j) {
                    int lj = jj * 8 + j;
                    int ch = (lj < 16) ? (c16 + lj) : (c8b + lj - 16);
                    float xn = (xa[lj] - mean) * rstd * ln_w[ch] + ln_b[ch];
                    pack[j] = (__bf16)xn;
                }
                int chbase = (jj < 2) ? (c16 + jj * 8) : c8b;
                *(bf16x8*)&At[row][chbase] = pack;
            }
        }
    }
    __syncthreads();   // At ready; rowlist reads done (Ht may overwrite)

    const int w  = t >> 6;
    const int l  = t & 63;
    const int lr = l & 15;
    const int lk = l >> 4;
    const int rb = w >> 1;    // row-block
    const int jh = w & 1;     // col-half

    f32x4 acc2[3];
    #pragma unroll
    for (int j = 0; j < 3; ++j) acc2[j] = (f32x4){0.f, 0.f, 0.f, 0.f};

    #pragma unroll
    for (int h = 0; h < 2; ++h) {
        // ---- GEMM1 half: [32,96] @ [96,192] ----
        f32x4 acc[6];
        #pragma unroll
        for (int j = 0; j < 6; ++j) acc[j] = (f32x4){0.f, 0.f, 0.f, 0.f};

        #pragma unroll
        for (int kk = 0; kk < 3; ++kk) {
            bf16x8 a = *(const bf16x8*)&At[rb*16 + lr][kk*32 + lk*8];
            #pragma unroll
            for (int j = 0; j < 6; ++j) {
                int col = h*192 + jh*96 + j*16 + lr;
                bf16x8 b = *(const bf16x8*)&w1t[col * DIM + kk*32 + lk*8];
                acc[j] = __builtin_amdgcn_mfma_f32_16x16x32_bf16(a, b, acc[j], 0, 0, 0);
            }
        }

        if (h == 1) __syncthreads();

        // ---- bias + exact GELU -> Ht half ----
        #pragma unroll
        for (int j = 0; j < 6; ++j) {
            int col = h*192 + jh*96 + j*16 + lr;
            float bb = b1[col];
            #pragma unroll
            for (int r = 0; r < 4; ++r) {
                float vv = acc[j][r] + bb;
                float ge = 0.5f * vv * (1.f + erff(vv * 0.70710678f));
                Ht[rb*16 + lk*4 + r][jh*96 + j*16 + lr] = __float2bfloat16(ge);
            }
        }
        __syncthreads();

        // ---- GEMM2 partial: [32,192] @ [192,96] ----
        #pragma unroll
        for (int kk = 0; kk < 6; ++kk) {
            bf16x8 a = *(const bf16x8*)&Ht[rb*16 + lr][kk*32 + lk*8];
            #pragma unroll
            for (int j = 0; j < 3; ++j) {
                int col = jh*48 + j*16 + lr;
                bf16x8 b = *(const bf16x8*)&w2t[col * HID + (h*6 + kk)*32 + lk*8];
                acc2[j] = __builtin_amdgcn_mfma_f32_16x16x32_bf16(a, b, acc2[j], 0, 0, 0);
            }
        }
    }

    // ---- epilogue: + b2 + residual (bf16 feats), NT store ----
    #pragma unroll
    for (int j = 0; j < 3; ++j) {
        int col = jh*48 + j*16 + lr;
        float bb = b2[col];
        #pragma unroll
        for (int r = 0; r < 4; ++r) {
            int grow = blk * TM + rb*16 + lk*4 + r;
            int off = grow * DIM + col;
            float res = (float)featsb[off];
            __builtin_nontemporal_store(acc2[j][r] + bb + res, &out[off]);
        }
    }
}

extern "C" void kernel_launch(void* const* d_in, const int* in_sizes, int n_in,
                              void* d_out, int out_size, void* d_ws, size_t ws_size,
                              hipStream_t stream) {
    const float* feats = (const float*)d_in[0];
    const float* w_dw  = (const float*)d_in[1];
    const float* b_dw  = (const float*)d_in[2];
    const float* ln_w  = (const float*)d_in[3];
    const float* ln_b  = (const float*)d_in[4];
    const float* w1    = (const float*)d_in[5];
    const float* b1    = (const float*)d_in[6];
    const float* w2    = (const float*)d_in[7];
    const float* b2    = (const float*)d_in[8];
    const int* in_idx  = (const int*)d_in[9];
    const int* out_idx = (const int*)d_in[10];
    const int* k_idx   = (const int*)d_in[11];
    float* out = (float*)d_out;

    char* ws = (char*)d_ws;
    unsigned* sb = (unsigned*)ws;                                  // 25,600,000
    int* bcnt = (int*)(ws + 25600000);                             //    200,000
    __hip_bfloat16* w1t = (__hip_bfloat16*)(ws + 25800000);        //     73,728
    __hip_bfloat16* w2t = (__hip_bfloat16*)(ws + 25873728);        //     73,728
    unsigned* wdw8 = (unsigned*)(ws + 25947456);                   //     32,928
    __bf16* featsb = (__bf16*)(ws + 25980384);                     // 38,400,000
    unsigned* featsf8 = (unsigned*)(ws + 64380384);                // 19,200,000 (~83.6MB)

    prep<<<(NVOX * DIM / 4) / 256, 256, 0, stream>>>(feats, w1, w2, w_dw,
                                                     featsb, featsf8, w1t, w2t, wdw8, bcnt);
    scatter_B<<<NEDGE / 4 / 256, 256, 0, stream>>>((const i32x4*)in_idx,
                                                   (const i32x4*)out_idx,
                                                   (const i32x4*)k_idx, bcnt, sb);
    fused_all<<<NBKT, 256, 0, stream>>>((const unsigned char*)featsf8, featsb, wdw8,
                                        b_dw, ln_w, ln_b, w1t, b1, w2t, b2, sb, bcnt, out);
}

// Round 18
// 448.287 us; speedup vs baseline: 1.1897x; 1.1897x over previous
//
#include <hip/hip_runtime.h>
#include <hip/hip_bf16.h>

#define NVOX 200000
#define DIM 96
#define KVOL 343
#define NEDGE 3200000
#define HID 384
#define TM 32
#define NBKT (NVOX / TM)        // 6250 block-buckets
#define SBCAP 128               // per-(bucket,xcd) capacity
#define ROWCAP 48               // per-voxel capacity; mean 16
#define XCC_IMM 63508           // hwreg(HW_REG_XCC_ID=20, offset 0, size 32)
#define W8DW (KVOL * DIM / 4)   // 8232 dwords of fp8 w_dw

typedef __attribute__((ext_vector_type(8))) __bf16 bf16x8;
typedef __attribute__((ext_vector_type(4))) __bf16 bf16x4;
typedef __attribute__((ext_vector_type(4))) float f32x4;
typedef __attribute__((ext_vector_type(2))) float f32x2;
typedef __attribute__((ext_vector_type(4))) int i32x4;
typedef __attribute__((ext_vector_type(4))) unsigned u32x4;
typedef __attribute__((ext_vector_type(2))) unsigned u32x2;

// ---------------- prep: feats->bf16 + fp8, w_dw->fp8, w1/w2->bf16 transposed ----------------
__global__ void prep(const float* __restrict__ feats, const float* __restrict__ w1,
                     const float* __restrict__ w2, const float* __restrict__ w_dw,
                     __bf16* __restrict__ featsb, unsigned* __restrict__ featsf8,
                     __hip_bfloat16* __restrict__ w1t, __hip_bfloat16* __restrict__ w2t,
                     unsigned* __restrict__ wdw8, int* __restrict__ bcnt) {
    int t = blockIdx.x * 256 + threadIdx.x;   // NVOX*DIM/4 = 4.8M exact
    f32x4 v = __builtin_nontemporal_load((const f32x4*)(feats + t * 4));
    bf16x4 o;
    o[0] = (__bf16)v.x; o[1] = (__bf16)v.y; o[2] = (__bf16)v.z; o[3] = (__bf16)v.w;
    __builtin_nontemporal_store(o, (bf16x4*)(featsb + t * 4));
    int pk = __builtin_amdgcn_cvt_pk_fp8_f32(v.x, v.y, 0, false);
    pk = __builtin_amdgcn_cvt_pk_fp8_f32(v.z, v.w, pk, true);
    __builtin_nontemporal_store((unsigned)pk, &featsf8[t]);
    if (t < HID * DIM) {
        int n1 = t / DIM, k1 = t % DIM;
        w1t[t] = __float2bfloat16(w1[k1 * HID + n1]);
        int n2 = t / HID, k2 = t % HID;
        w2t[t] = __float2bfloat16(w2[k2 * DIM + n2]);
    }
    if (t < W8DW) {
        f32x4 w = *(const f32x4*)(w_dw + t * 4);
        int wp = __builtin_amdgcn_cvt_pk_fp8_f32(w.x, w.y, 0, false);
        wp = __builtin_amdgcn_cvt_pk_fp8_f32(w.z, w.w, wp, true);
        wdw8[t] = (unsigned)wp;
    }
    if (t < NBKT * 8) bcnt[t] = 0;
}

// ---------------- scatter into XCD-private block-buckets ----------------
__global__ void scatter_B(const i32x4* __restrict__ in4, const i32x4* __restrict__ out4,
                          const i32x4* __restrict__ k4, int* __restrict__ bcnt,
                          unsigned* __restrict__ sb) {
    int t = blockIdx.x * 256 + threadIdx.x;   // NEDGE/4 exact
    unsigned xcd = (unsigned)__builtin_amdgcn_s_getreg(XCC_IMM) & 7u;
    i32x4 i = __builtin_nontemporal_load(&in4[t]);
    i32x4 o = __builtin_nontemporal_load(&out4[t]);
    i32x4 k = __builtin_nontemporal_load(&k4[t]);
    int b, d;
    b = ((unsigned)o.x >> 5) * 8 + xcd;
    d = atomicAdd(&bcnt[b], 1);
    if (d < SBCAP) sb[b * SBCAP + d] = (unsigned)i.x | ((unsigned)k.x << 18) | ((unsigned)(o.x & 31) << 27);
    b = ((unsigned)o.y >> 5) * 8 + xcd;
    d = atomicAdd(&bcnt[b], 1);
    if (d < SBCAP) sb[b * SBCAP + d] = (unsigned)i.y | ((unsigned)k.y << 18) | ((unsigned)(o.y & 31) << 27);
    b = ((unsigned)o.z >> 5) * 8 + xcd;
    d = atomicAdd(&bcnt[b], 1);
    if (d < SBCAP) sb[b * SBCAP + d] = (unsigned)i.z | ((unsigned)k.z << 18) | ((unsigned)(o.z & 31) << 27);
    b = ((unsigned)o.w >> 5) * 8 + xcd;
    d = atomicAdd(&bcnt[b], 1);
    if (d < SBCAP) sb[b * SBCAP + d] = (unsigned)i.w | ((unsigned)k.w << 18) | ((unsigned)(o.w & 31) << 27);
}

// ---------------- fused sort + fp8-gather (f and w both fp8 VMEM) + LN + MLP ----------------
__global__ __launch_bounds__(256, 4) void fused_all(
    const unsigned char* __restrict__ featsf8, const __bf16* __restrict__ featsb,
    const unsigned char* __restrict__ wdw8, const float* __restrict__ b_dw,
    const float* __restrict__ ln_w, const float* __restrict__ ln_b,
    const __hip_bfloat16* __restrict__ w1t, const float* __restrict__ b1,
    const __hip_bfloat16* __restrict__ w2t, const float* __restrict__ b2,
    const unsigned* __restrict__ sb, const int* __restrict__ bcnt,
    float* __restrict__ out)
{
    __shared__ __hip_bfloat16 At[TM][104];                 //  6,656 B
    __shared__ __align__(16) char shb[TM * 200 * 2];       // 12,800 B: rowlist+rowcnt | Ht half
    __hip_bfloat16 (*Ht)[200] = (__hip_bfloat16 (*)[200])shb;
    unsigned (*rowlist)[ROWCAP] = (unsigned (*)[ROWCAP])shb;   // 6,144 B
    int* rowcnt = (int*)(shb + 32 * ROWCAP * 4);               //   128 B

    const int t   = threadIdx.x;
    const int blk = blockIdx.x;

    // ---- counting-sort the block's 8 sub-buckets into per-row LDS lists ----
    if (t < 32) rowcnt[t] = 0;
    __syncthreads();
    #pragma unroll
    for (int q = 0; q < 8; ++q) {
        int cq = bcnt[blk * 8 + q];
        if (cq > SBCAP) cq = SBCAP;
        const unsigned* reg = sb + (blk * 8 + q) * SBCAP;
        for (int i = t; i < cq; i += 256) {
            unsigned r = reg[i];
            int row = (int)(r >> 27);
            int d = atomicAdd(&rowcnt[row], 1);
            if (d < ROWCAP) rowlist[row][d] = r;
        }
    }
    __syncthreads();

    // ---- gather: 8 threads/voxel = 4 parts x 2 edge-halves ----
    // part p owns channels [p*16, p*16+16) U [64+p*8, 64+p*8+8)
    {
        const int row  = t >> 3;        // 0..31
        const int sub  = t & 7;
        const int part = sub & 3;
        const int half = sub >> 2;
        const int c16  = part * 16;
        const int c8b  = 64 + part * 8;

        int c = rowcnt[row];
        if (c > ROWCAP) c = ROWCAP;

        float xa[24];
        #pragma unroll
        for (int j = 0; j < 24; ++j) xa[j] = 0.f;

        const unsigned char* f8base = featsf8;
        const unsigned char* w8base = wdw8;
        const unsigned* rl = rowlist[row];

        const int e_lo = half ? (c >> 1) : 0;
        const int e_hi = half ? c : (c >> 1);

#define LDE(FQ, FD, WQ, WD, ee) { unsigned rr = rl[ee]; \
        const unsigned char* f8r = f8base + (unsigned)(rr & 0x3FFFFu) * 96u; \
        const unsigned char* w8r = w8base + ((rr >> 18) & 0x1FFu) * 96u; \
        FQ = *(const u32x4*)(f8r + c16); \
        FD = *(const u32x2*)(f8r + c8b); \
        WQ = *(const u32x4*)(w8r + c16); \
        WD = *(const u32x2*)(w8r + c8b); }

#define ACC(FQ, FD, WQ, WD) { \
        float fa[24], wa[24]; \
        *(f32x2*)&fa[0]  = __builtin_amdgcn_cvt_pk_f32_fp8(FQ.x, false); \
        *(f32x2*)&fa[2]  = __builtin_amdgcn_cvt_pk_f32_fp8(FQ.x, true);  \
        *(f32x2*)&fa[4]  = __builtin_amdgcn_cvt_pk_f32_fp8(FQ.y, false); \
        *(f32x2*)&fa[6]  = __builtin_amdgcn_cvt_pk_f32_fp8(FQ.y, true);  \
        *(f32x2*)&fa[8]  = __builtin_amdgcn_cvt_pk_f32_fp8(FQ.z, false); \
        *(f32x2*)&fa[10] = __builtin_amdgcn_cvt_pk_f32_fp8(FQ.z, true);  \
        *(f32x2*)&fa[12] = __builtin_amdgcn_cvt_pk_f32_fp8(FQ.w, false); \
        *(f32x2*)&fa[14] = __builtin_amdgcn_cvt_pk_f32_fp8(FQ.w, true);  \
        *(f32x2*)&fa[16] = __builtin_amdgcn_cvt_pk_f32_fp8(FD.x, false); \
        *(f32x2*)&fa[18] = __builtin_amdgcn_cvt_pk_f32_fp8(FD.x, true);  \
        *(f32x2*)&fa[20] = __builtin_amdgcn_cvt_pk_f32_fp8(FD.y, false); \
        *(f32x2*)&fa[22] = __builtin_amdgcn_cvt_pk_f32_fp8(FD.y, true);  \
        *(f32x2*)&wa[0]  = __builtin_amdgcn_cvt_pk_f32_fp8(WQ.x, false); \
        *(f32x2*)&wa[2]  = __builtin_amdgcn_cvt_pk_f32_fp8(WQ.x, true);  \
        *(f32x2*)&wa[4]  = __builtin_amdgcn_cvt_pk_f32_fp8(WQ.y, false); \
        *(f32x2*)&wa[6]  = __builtin_amdgcn_cvt_pk_f32_fp8(WQ.y, true);  \
        *(f32x2*)&wa[8]  = __builtin_amdgcn_cvt_pk_f32_fp8(WQ.z, false); \
        *(f32x2*)&wa[10] = __builtin_amdgcn_cvt_pk_f32_fp8(WQ.z, true);  \
        *(f32x2*)&wa[12] = __builtin_amdgcn_cvt_pk_f32_fp8(WQ.w, false); \
        *(f32x2*)&wa[14] = __builtin_amdgcn_cvt_pk_f32_fp8(WQ.w, true);  \
        *(f32x2*)&wa[16] = __builtin_amdgcn_cvt_pk_f32_fp8(WD.x, false); \
        *(f32x2*)&wa[18] = __builtin_amdgcn_cvt_pk_f32_fp8(WD.x, true);  \
        *(f32x2*)&wa[20] = __builtin_amdgcn_cvt_pk_f32_fp8(WD.y, false); \
        *(f32x2*)&wa[22] = __builtin_amdgcn_cvt_pk_f32_fp8(WD.y, true);  \
        _Pragma("unroll") for (int j = 0; j < 24; ++j) xa[j] += fa[j] * wa[j]; }

        u32x4 Aq, Bq, Awq, Bwq; u32x2 Ad, Bd, Awd, Bwd;
        int e = e_lo;
        if (e + 2 <= e_hi) {
            LDE(Aq, Ad, Awq, Awd, e); LDE(Bq, Bd, Bwq, Bwd, e + 1);
            e += 2;
            for (; e + 2 <= e_hi; e += 2) {
                u32x4 Cq, Dq, Cwq, Dwq; u32x2 Cd, Dd, Cwd, Dwd;
                LDE(Cq, Cd, Cwq, Cwd, e); LDE(Dq, Dd, Dwq, Dwd, e + 1);
                ACC(Aq, Ad, Awq, Awd); ACC(Bq, Bd, Bwq, Bwd);
                Aq = Cq; Ad = Cd; Awq = Cwq; Awd = Cwd;
                Bq = Dq; Bd = Dd; Bwq = Dwq; Bwd = Dwd;
            }
            ACC(Aq, Ad, Awq, Awd); ACC(Bq, Bd, Bwq, Bwd);
        }
        if (e < e_hi) {
            LDE(Aq, Ad, Awq, Awd, e);
            ACC(Aq, Ad, Awq, Awd);
        }
#undef LDE
#undef ACC

        // combine edge-halves (lane bit 2)
        #pragma unroll
        for (int j = 0; j < 24; ++j) xa[j] += __shfl_xor(xa[j], 4);

        // + b_dw, LayerNorm stats across 4 parts (lane bits 0-1)
        float s = 0.f, s2 = 0.f;
        #pragma unroll
        for (int j = 0; j < 24; ++j) {
            int ch = (j < 16) ? (c16 + j) : (c8b + j - 16);
            float x = xa[j] + b_dw[ch];
            xa[j] = x;
            s += x; s2 += x * x;
        }
        s  += __shfl_xor(s, 1);  s  += __shfl_xor(s, 2);
        s2 += __shfl_xor(s2, 1); s2 += __shfl_xor(s2, 2);
        float mean = s * (1.f / 96.f);
        float var  = s2 * (1.f / 96.f) - mean * mean;
        float rstd = rsqrtf(var + 1e-6f);

        if (half == 0) {
            #pragma unroll
            for (int jj = 0; jj < 3; ++jj) {
                bf16x8 pack;
                #pragma unroll
                for (int j = 0; j < 8; ++j) {
                    int lj = jj * 8 + j;
                    int ch = (lj < 16) ? (c16 + lj) : (c8b + lj - 16);
                    float xn = (xa[lj] - mean) * rstd * ln_w[ch] + ln_b[ch];
                    pack[j] = (__bf16)xn;
                }
                int chbase = (jj < 2) ? (c16 + jj * 8) : c8b;
                *(bf16x8*)&At[row][chbase] = pack;
            }
        }
    }
    __syncthreads();   // At ready; rowlist reads done (Ht may overwrite)

    const int w  = t >> 6;
    const int l  = t & 63;
    const int lr = l & 15;
    const int lk = l >> 4;
    const int rb = w >> 1;    // row-block
    const int jh = w & 1;     // col-half

    f32x4 acc2[3];
    #pragma unroll
    for (int j = 0; j < 3; ++j) acc2[j] = (f32x4){0.f, 0.f, 0.f, 0.f};

    #pragma unroll
    for (int h = 0; h < 2; ++h) {
        // ---- GEMM1 half: [32,96] @ [96,192] ----
        f32x4 acc[6];
        #pragma unroll
        for (int j = 0; j < 6; ++j) acc[j] = (f32x4){0.f, 0.f, 0.f, 0.f};

        #pragma unroll
        for (int kk = 0; kk < 3; ++kk) {
            bf16x8 a = *(const bf16x8*)&At[rb*16 + lr][kk*32 + lk*8];
            #pragma unroll
            for (int j = 0; j < 6; ++j) {
                int col = h*192 + jh*96 + j*16 + lr;
                bf16x8 b = *(const bf16x8*)&w1t[col * DIM + kk*32 + lk*8];
                acc[j] = __builtin_amdgcn_mfma_f32_16x16x32_bf16(a, b, acc[j], 0, 0, 0);
            }
        }

        if (h == 1) __syncthreads();

        // ---- bias + exact GELU -> Ht half ----
        #pragma unroll
        for (int j = 0; j < 6; ++j) {
            int col = h*192 + jh*96 + j*16 + lr;
            float bb = b1[col];
            #pragma unroll
            for (int r = 0; r < 4; ++r) {
                float vv = acc[j][r] + bb;
                float ge = 0.5f * vv * (1.f + erff(vv * 0.70710678f));
                Ht[rb*16 + lk*4 + r][jh*96 + j*16 + lr] = __float2bfloat16(ge);
            }
        }
        __syncthreads();

        // ---- GEMM2 partial: [32,192] @ [192,96] ----
        #pragma unroll
        for (int kk = 0; kk < 6; ++kk) {
            bf16x8 a = *(const bf16x8*)&Ht[rb*16 + lr][kk*32 + lk*8];
            #pragma unroll
            for (int j = 0; j < 3; ++j) {
                int col = jh*48 + j*16 + lr;
                bf16x8 b = *(const bf16x8*)&w2t[col * HID + (h*6 + kk)*32 + lk*8];
                acc2[j] = __builtin_amdgcn_mfma_f32_16x16x32_bf16(a, b, acc2[j], 0, 0, 0);
            }
        }
    }

    // ---- epilogue: + b2 + residual (bf16 feats), NT store ----
    #pragma unroll
    for (int j = 0; j < 3; ++j) {
        int col = jh*48 + j*16 + lr;
        float bb = b2[col];
        #pragma unroll
        for (int r = 0; r < 4; ++r) {
            int grow = blk * TM + rb*16 + lk*4 + r;
            int off = grow * DIM + col;
            float res = (float)featsb[off];
            __builtin_nontemporal_store(acc2[j][r] + bb + res, &out[off]);
        }
    }
}

extern "C" void kernel_launch(void* const* d_in, const int* in_sizes, int n_in,
                              void* d_out, int out_size, void* d_ws, size_t ws_size,
                              hipStream_t stream) {
    const float* feats = (const float*)d_in[0];
    const float* w_dw  = (const float*)d_in[1];
    const float* b_dw  = (const float*)d_in[2];
    const float* ln_w  = (const float*)d_in[3];
    const float* ln_b  = (const float*)d_in[4];
    const float* w1    = (const float*)d_in[5];
    const float* b1    = (const float*)d_in[6];
    const float* w2    = (const float*)d_in[7];
    const float* b2    = (const float*)d_in[8];
    const int* in_idx  = (const int*)d_in[9];
    const int* out_idx = (const int*)d_in[10];
    const int* k_idx   = (const int*)d_in[11];
    float* out = (float*)d_out;

    char* ws = (char*)d_ws;
    unsigned* sb = (unsigned*)ws;                                  // 25,600,000
    int* bcnt = (int*)(ws + 25600000);                             //    200,000
    __hip_bfloat16* w1t = (__hip_bfloat16*)(ws + 25800000);        //     73,728
    __hip_bfloat16* w2t = (__hip_bfloat16*)(ws + 25873728);        //     73,728
    unsigned* wdw8 = (unsigned*)(ws + 25947456);                   //     32,928
    __bf16* featsb = (__bf16*)(ws + 25980384);                     // 38,400,000
    unsigned* featsf8 = (unsigned*)(ws + 64380384);                // 19,200,000 (~83.6MB)

    prep<<<(NVOX * DIM / 4) / 256, 256, 0, stream>>>(feats, w1, w2, w_dw,
                                                     featsb, featsf8, w1t, w2t, wdw8, bcnt);
    scatter_B<<<NEDGE / 4 / 256, 256, 0, stream>>>((const i32x4*)in_idx,
                                                   (const i32x4*)out_idx,
                                                   (const i32x4*)k_idx, bcnt, sb);
    fused_all<<<NBKT, 256, 0, stream>>>((const unsigned char*)featsf8, featsb,
                                        (const unsigned char*)wdw8,
                                        b_dw, ln_w, ln_b, w1t, b1, w2t, b2, sb, bcnt, out);
}